// Round 20
// baseline (62.088 us; speedup 1.0000x reference)
//
#include <hip/hip_runtime.h>
#include <hip/hip_bf16.h>

typedef __attribute__((ext_vector_type(8))) short short8;
typedef __attribute__((ext_vector_type(4))) float f32x4;

#define N_BATCH 8
#define N_ROWS 32768
#define DDIM 128
#define KSLOT 64
#define EH 128
#define TPB 8                  // tiles per block
#define BLK_PER_B 64           // 512 tiles / TPB
#define SCALE 0.08838834764831845f

__device__ inline unsigned short f2bf(float f){
  unsigned int u = __builtin_bit_cast(unsigned int, f);
  u = (u + 0x7FFFu + ((u >> 16) & 1u)) >> 16;
  return (unsigned short)u;
}
__device__ inline float bf2f(unsigned short h){
  unsigned int u = ((unsigned int)h) << 16;
  return __builtin_bit_cast(float, u);
}

__device__ inline unsigned int pk2bf(float lo, float hi){
  __hip_bfloat162 h = __float22bfloat162_rn(float2{lo, hi});
  unsigned int u;
  __builtin_memcpy(&u, &h, 4);
  return u;
}

// lgkm-only barrier: protects LDS produce->consume without draining vmcnt,
// so cross-tile global prefetch stays in flight across the barrier.
__device__ inline void lds_barrier(){
  asm volatile("s_waitcnt lgkmcnt(0)" ::: "memory");
  __builtin_amdgcn_s_barrier();
}

// ---- prep: qf = scale*(S@Wq)@Wk^T in MFMA B-fragment-swizzled order ----
// qf element for (slot=st*16+l15, d=step*32+g*8+e) lives at
// b*8192 + ((st*4+step)*64 + g*16 + l15)*8 + e  -> main reads base+lane*8.
__global__ void prep_qk_kernel(const float* __restrict__ S, const float* __restrict__ Wq,
                               const float* __restrict__ Wk, unsigned short* __restrict__ qf){
  int bs = blockIdx.x;             // 0..511 = b*64 + slot
  __shared__ float srow[128];
  __shared__ float qrow[128];
  __shared__ float krow[128];
  int t = threadIdx.x;             // 128 threads
  srow[t] = S[bs * 128 + t];
  __syncthreads();
  float acc = 0.f;
  #pragma unroll 8
  for(int h = 0; h < 128; ++h) acc += srow[h] * Wq[h * 128 + t];   // q[s,e=t]
  qrow[t] = acc;
  __syncthreads();
  float acc2 = 0.f;
  #pragma unroll 8
  for(int e = 0; e < 128; ++e) acc2 += qrow[e] * Wk[t * 128 + e];  // qk[s,d=t]
  krow[t] = acc2 * SCALE;
  __syncthreads();
  if(t < 16){
    int step = t >> 2, g = t & 3;
    int b = bs >> 6, s = bs & 63;
    int st = s >> 4, l15 = s & 15;
    short8 v;
    #pragma unroll
    for(int e = 0; e < 8; ++e) v[e] = (short)f2bf(krow[step * 32 + g * 8 + e]);
    *reinterpret_cast<short8*>(qf + (size_t)b * 8192 +
        (size_t)(((st * 4 + step) * 64 + g * 16 + l15) * 8)) = v;
  }
}

// one tile for buffer XBUF holding tile TT, writing/reading LDS buffer BUF;
// prefetches tile TT+2 into XBUF after the pack consumes it.
#define TILE_BODY(XBUF, TT, BUF)                                                   \
  {                                                                                \
    _Pragma("unroll")                                                              \
    for(int m = 0; m < 4; ++m){                                                    \
      const int nb = wr0 + 4 * m;                                                  \
      unsigned int p0a = pk2bf(XBUF[2*m][0],   XBUF[2*m][1]);                      \
      unsigned int p0b = pk2bf(XBUF[2*m][2],   XBUF[2*m][3]);                      \
      unsigned int p1a = pk2bf(XBUF[2*m+1][0], XBUF[2*m+1][1]);                    \
      unsigned int p1b = pk2bf(XBUF[2*m+1][2], XBUF[2*m+1][3]);                    \
      uint2 s0; s0.x = p0a; s0.y = p0b;                                            \
      uint2 s1; s1.x = p1a; s1.y = p1b;                                            \
      *reinterpret_cast<uint2*>(&Xs[nb + half][4 * l31])     = s0;                 \
      *reinterpret_cast<uint2*>(&Xs[nb + 2 + half][4 * l31]) = s1;                 \
      unsigned int q0a = (unsigned int)__shfl_xor((int)p0a, 32);                   \
      unsigned int q0b = (unsigned int)__shfl_xor((int)p0b, 32);                   \
      unsigned int q1a = (unsigned int)__shfl_xor((int)p1a, 32);                   \
      unsigned int q1b = (unsigned int)__shfl_xor((int)p1b, 32);                   \
      unsigned int A = half ? q0b : p0a;                                           \
      unsigned int B = half ? p0b : q0a;                                           \
      unsigned int C = half ? q1b : p1a;                                           \
      unsigned int D = half ? p1b : q1a;                                           \
      const int d0 = 4 * l31 + 2 * half;                                           \
      unsigned int wlo0 = __builtin_amdgcn_perm(B, A, 0x05040100u);                \
      unsigned int wlo1 = __builtin_amdgcn_perm(D, C, 0x05040100u);                \
      unsigned int whi0 = __builtin_amdgcn_perm(B, A, 0x07060302u);                \
      unsigned int whi1 = __builtin_amdgcn_perm(D, C, 0x07060302u);                \
      *reinterpret_cast<unsigned int*>(&Xt[BUF][d0][nb])         = wlo0;           \
      *reinterpret_cast<unsigned int*>(&Xt[BUF][d0][nb + 2])     = wlo1;           \
      *reinterpret_cast<unsigned int*>(&Xt[BUF][d0 + 1][nb])     = whi0;           \
      *reinterpret_cast<unsigned int*>(&Xt[BUF][d0 + 1][nb + 2]) = whi1;           \
    }                                                                              \
    if((TT) + 2 < TPB){                                                            \
      const float* xp = xw + (size_t)((TT) + 2) * 64 * DDIM;                       \
      _Pragma("unroll")                                                            \
      for(int c = 0; c < 8; ++c)                                                   \
        XBUF[c] = *reinterpret_cast<const f32x4*>(xp + c * 256);                   \
    }                                                                              \
    f32x4 macc[4];                                                                 \
    _Pragma("unroll")                                                              \
    for(int i = 0; i < 4; ++i) macc[i] = {0.f,0.f,0.f,0.f};                        \
    __builtin_amdgcn_s_setprio(1);                                                 \
    _Pragma("unroll")                                                              \
    for(int step = 0; step < 4; ++step){                                           \
      short8 a = *reinterpret_cast<const short8*>(&Xs[wr0 + l15][step * 32 + g * 8]); \
      _Pragma("unroll")                                                            \
      for(int st = 0; st < 4; ++st)                                                \
        macc[st] = __builtin_amdgcn_mfma_f32_16x16x32_bf16(a, bq[st][step], macc[st], 0, 0, 0); \
    }                                                                              \
    __builtin_amdgcn_s_setprio(0);                                                 \
    float att[4][4];                                                               \
    float rinv[4];                                                                 \
    _Pragma("unroll")                                                              \
    for(int st = 0; st < 4; ++st){                                                 \
      _Pragma("unroll")                                                            \
      for(int r = 0; r < 4; ++r)                                                   \
        att[st][r] = __builtin_amdgcn_rcpf(1.f + __expf(-macc[st][r])) + 1e-8f;    \
    }                                                                              \
    _Pragma("unroll")                                                              \
    for(int r = 0; r < 4; ++r){                                                    \
      float s = att[0][r] + att[1][r] + att[2][r] + att[3][r];                     \
      s += __shfl_xor(s, 1); s += __shfl_xor(s, 2);                                \
      s += __shfl_xor(s, 4); s += __shfl_xor(s, 8);                                \
      rinv[r] = __builtin_amdgcn_rcpf(s);                                          \
    }                                                                              \
    _Pragma("unroll")                                                              \
    for(int st = 0; st < 4; ++st){                                                 \
      unsigned int u0 = pk2bf(att[st][0] * rinv[0], att[st][1] * rinv[1]);         \
      unsigned int u1 = pk2bf(att[st][2] * rinv[2], att[st][3] * rinv[3]);         \
      ushort4 wp;                                                                  \
      __builtin_memcpy(&wp, &u0, 4);                                               \
      __builtin_memcpy(reinterpret_cast<char*>(&wp) + 4, &u1, 4);                  \
      *reinterpret_cast<ushort4*>(&WTs[BUF][st * 16 + l15][wave * 16 + g * 4]) = wp; \
    }                                                                              \
    lds_barrier();                                                                 \
    __builtin_amdgcn_s_setprio(1);                                                 \
    _Pragma("unroll")                                                              \
    for(int ns = 0; ns < 2; ++ns){                                                 \
      short8 af = *reinterpret_cast<const short8*>(&WTs[BUF][wr0 + l15][ns * 32 + g * 8]); \
      _Pragma("unroll")                                                            \
      for(int et = 0; et < 8; ++et){                                               \
        short8 bf = *reinterpret_cast<const short8*>(&Xt[BUF][et * 16 + l15][ns * 32 + g * 8]); \
        sacc[et] = __builtin_amdgcn_mfma_f32_16x16x32_bf16(af, bf, sacc[et], 0, 0, 0); \
      }                                                                            \
    }                                                                              \
    __builtin_amdgcn_s_setprio(0);                                                 \
  }

// ---- main fused kernel: shared-T, bq regs, dbuf LDS, depth-2 prefetch ----
__global__ __launch_bounds__(256, 1) void sse_main_kernel(
    const float* __restrict__ X, const unsigned short* __restrict__ qf,
    unsigned short* __restrict__ partials)
{
  __shared__ unsigned short Xs[64][136];      // X row-major [n][d]; reused by epilogue
  __shared__ unsigned short Xt[2][128][70];   // X transposed [d][n], double-buffered
  __shared__ unsigned short WTs[2][64][72];   // W^T [slot][n], double-buffered

  const int tid  = threadIdx.x;
  const int wave = tid >> 6;
  const int lane = tid & 63;
  const int l15  = lane & 15;
  const int g    = lane >> 4;
  const int l31  = lane & 31;
  const int half = lane >> 5;

  const int b  = blockIdx.x / BLK_PER_B;
  const int tb = blockIdx.x % BLK_PER_B;

  const float* Xb = X + (size_t)b * N_ROWS * DDIM;
  const unsigned short* qkb = qf + (size_t)b * 8192;

  // ---- hoist qk B-fragments into registers (coalesced 16B/lane, once) ----
  short8 bq[4][4];
  #pragma unroll
  for(int st = 0; st < 4; ++st)
    #pragma unroll
    for(int step = 0; step < 4; ++step)
      bq[st][step] = *reinterpret_cast<const short8*>(qkb +
          (size_t)(((st * 4 + step) * 64 + lane) * 8));

  f32x4 sacc[8];   // T[slot=wave*16+g*4+r][d=et*16+l15]
  #pragma unroll
  for(int i = 0; i < 8; ++i) sacc[i] = {0.f, 0.f, 0.f, 0.f};

  const float* xw = Xb + (size_t)(tb * TPB * 64 + wave * 16) * DDIM + lane * 4;

  // depth-2 ping-pong prefetch: xa = even tiles, xb = odd tiles
  f32x4 xa[8], xb[8];
  #pragma unroll
  for(int c = 0; c < 8; ++c)
    xa[c] = *reinterpret_cast<const f32x4*>(xw + c * 256);
  #pragma unroll
  for(int c = 0; c < 8; ++c)
    xb[c] = *reinterpret_cast<const f32x4*>(xw + 64 * DDIM + c * 256);

  const int wr0 = wave * 16;

  #pragma unroll
  for(int tq = 0; tq < TPB; tq += 2){
    TILE_BODY(xa, tq, 0)
    TILE_BODY(xb, tq + 1, 1)
  }

  // ---- epilogue: bf16 partials via 2-phase LDS staging (Xs region dead) ----
  lds_barrier();                       // all phase-A reads of Xs complete
  float* stgf = (float*)(&Xs[0][0]);   // 16 KB stage region
  unsigned short* po = partials + (size_t)blockIdx.x * (KSLOT * EH);
  #pragma unroll
  for(int rd = 0; rd < 2; ++rd){
    #pragma unroll
    for(int et = 0; et < 4; ++et){
      const int ee = rd * 4 + et;
      #pragma unroll
      for(int r = 0; r < 4; ++r)
        stgf[(wr0 + g * 4 + r) * 64 + et * 16 + l15] = sacc[ee][r];
    }
    lds_barrier();
    {
      int base = tid * 16;             // 0..4095
      int slot = base >> 6;
      int d0   = base & 63;
      union { short8 s; unsigned int u[4]; } pk0, pk1;
      #pragma unroll
      for(int j = 0; j < 4; ++j){
        pk0.u[j] = pk2bf(stgf[base + 2*j],     stgf[base + 2*j + 1]);
        pk1.u[j] = pk2bf(stgf[base + 8 + 2*j], stgf[base + 8 + 2*j + 1]);
      }
      unsigned short* dst = po + slot * 128 + rd * 64 + d0;
      *reinterpret_cast<short8*>(dst)     = pk0.s;
      *reinterpret_cast<short8*>(dst + 8) = pk1.s;
    }
    lds_barrier();
  }
}

// ---- reduce: T[b][s][:] = sum over 64 bf16 block-partials, then out = T @ Wv ----
__global__ void reduce_kernel(const unsigned short* __restrict__ partials,
                              const float* __restrict__ Wv, float* __restrict__ out){
  int bs = blockIdx.x;             // 0..511 = b*64 + slot
  int b  = bs >> 6;
  int s  = bs & 63;
  __shared__ float Tl[128];
  int t = threadIdx.x;             // 128 threads = d, then e
  const unsigned short* pb = partials + (size_t)b * BLK_PER_B * (KSLOT * EH) + s * EH + t;
  float acc = 0.f;
  #pragma unroll 8
  for(int i = 0; i < BLK_PER_B; ++i)
    acc += bf2f(pb[(size_t)i * (KSLOT * EH)]);
  Tl[t] = acc;
  __syncthreads();
  float o = 0.f;
  #pragma unroll 8
  for(int d = 0; d < 128; ++d) o += Tl[d] * Wv[d * 128 + t];
  out[bs * 128 + t] = o;
}

extern "C" void kernel_launch(void* const* d_in, const int* in_sizes, int n_in,
                              void* d_out, int out_size, void* d_ws, size_t ws_size,
                              hipStream_t stream){
  const float* X  = (const float*)d_in[0];
  const float* S  = (const float*)d_in[1];
  const float* Wk = (const float*)d_in[2];
  const float* Wq = (const float*)d_in[3];
  const float* Wv = (const float*)d_in[4];
  float* out = (float*)d_out;

  char* ws = (char*)d_ws;
  unsigned short* qf       = (unsigned short*)(ws);           // 128 KB
  unsigned short* partials = (unsigned short*)(ws + 131072);  // 512 * 16 KB = 8.4 MB

  hipLaunchKernelGGL(prep_qk_kernel, dim3(512), dim3(128), 0, stream, S, Wq, Wk, qf);
  hipLaunchKernelGGL(sse_main_kernel, dim3(N_BATCH * BLK_PER_B), dim3(256), 0, stream,
                     X, qf, partials);
  hipLaunchKernelGGL(reduce_kernel, dim3(512), dim3(128), 0, stream, partials, Wv, out);
}

// Round 21
// 51.090 us; speedup vs baseline: 1.2153x; 1.2153x over previous
//
#include <hip/hip_runtime.h>
#include <hip/hip_bf16.h>

typedef __attribute__((ext_vector_type(8))) short short8;
typedef __attribute__((ext_vector_type(4))) short short4v;
typedef __attribute__((ext_vector_type(4))) float f32x4;

#define N_BATCH 8
#define N_ROWS 32768
#define DDIM 128
#define KSLOT 64
#define EH 128
#define TPB 8                  // tiles per block
#define BLK_PER_B 64           // 512 tiles / TPB
#define SCALE 0.08838834764831845f

__device__ inline unsigned short f2bf(float f){
  unsigned int u = __builtin_bit_cast(unsigned int, f);
  u = (u + 0x7FFFu + ((u >> 16) & 1u)) >> 16;
  return (unsigned short)u;
}
__device__ inline float bf2f(unsigned short h){
  unsigned int u = ((unsigned int)h) << 16;
  return __builtin_bit_cast(float, u);
}

__device__ inline unsigned int pk2bf(float lo, float hi){
  __hip_bfloat162 h = __float22bfloat162_rn(float2{lo, hi});
  unsigned int u;
  __builtin_memcpy(&u, &h, 4);
  return u;
}

__device__ inline void lds_barrier(){
  asm volatile("s_waitcnt lgkmcnt(0)" ::: "memory");
  __builtin_amdgcn_s_barrier();
}

// ---- prep: qk[b][s][d] = scale * (S[b,s,:]@Wq) @ Wk^T, bf16 linear ----
__global__ void prep_qk_kernel(const float* __restrict__ S, const float* __restrict__ Wq,
                               const float* __restrict__ Wk, unsigned short* __restrict__ qk){
  int bs = blockIdx.x;             // 0..511 = b*64 + slot
  __shared__ float srow[128];
  __shared__ float qrow[128];
  int t = threadIdx.x;             // 128 threads
  srow[t] = S[bs * 128 + t];
  __syncthreads();
  float acc = 0.f;
  #pragma unroll 8
  for(int h = 0; h < 128; ++h) acc += srow[h] * Wq[h * 128 + t];
  qrow[t] = acc;
  __syncthreads();
  float acc2 = 0.f;
  #pragma unroll 8
  for(int e = 0; e < 128; ++e) acc2 += qrow[e] * Wk[t * 128 + e];
  qk[bs * 128 + t] = f2bf(acc2 * SCALE);
}

// ---- main fused kernel: zero barriers in the tile loop; waves independent ----
__global__ __launch_bounds__(256, 1) void sse_main_kernel(
    const float* __restrict__ X, const unsigned short* __restrict__ qkg,
    unsigned short* __restrict__ partials)
{
  // manual carve of shared memory so the epilogue can reuse it
  __shared__ char smem[55296];     // qs 17408 | Xs 17408 | Xtw 20480
  unsigned short (*qs)[136]  = (unsigned short(*)[136])(smem);
  unsigned short (*Xs)[136]  = (unsigned short(*)[136])(smem + 17408);
  unsigned short (*Xtw)[20]  = (unsigned short(*)[20]) (smem + 34816); // [4*128][20]

  const int tid  = threadIdx.x;
  const int wave = tid >> 6;
  const int lane = tid & 63;
  const int l15  = lane & 15;
  const int g    = lane >> 4;
  const int l31  = lane & 31;
  const int half = lane >> 5;

  const int b  = blockIdx.x / BLK_PER_B;
  const int tb = blockIdx.x % BLK_PER_B;

  const float* Xb = X + (size_t)b * N_ROWS * DDIM;
  const unsigned short* qkb = qkg + b * KSLOT * EH;

  // ---- stage qk (16 KB) coalesced ----
  #pragma unroll
  for(int i = 0; i < 4; ++i){
    int o = (i * 256 + tid) * 8;
    *reinterpret_cast<short8*>(&qs[o >> 7][o & 127]) =
        *reinterpret_cast<const short8*>(qkb + o);
  }

  f32x4 sacc[4][8];   // T[slot=sta*16+g*4+r][d=et*16+l15], per-wave full T
  #pragma unroll
  for(int i = 0; i < 4; ++i)
    #pragma unroll
    for(int j = 0; j < 8; ++j) sacc[i][j] = {0.f, 0.f, 0.f, 0.f};

  const float* xw = Xb + (size_t)(tb * TPB * 64 + wave * 16) * DDIM + lane * 4;

  f32x4 xa[8];
  #pragma unroll
  for(int c = 0; c < 8; ++c)
    xa[c] = *reinterpret_cast<const f32x4*>(xw + c * 256);

  lds_barrier();    // qs visible; the ONLY barrier before the epilogue

  const int wr0 = wave * 16;
  unsigned short (*xtw)[20] = &Xtw[wave * 128];   // this wave's [128][20] scratch

  #pragma unroll
  for(int tt = 0; tt < TPB; ++tt){

    // ---- pack xa -> Xs (row-major) + xtw (transposed) via reg-exchange ----
    #pragma unroll
    for(int m = 0; m < 4; ++m){
      const int nb = wr0 + 4 * m;
      unsigned int p0a = pk2bf(xa[2*m][0],   xa[2*m][1]);
      unsigned int p0b = pk2bf(xa[2*m][2],   xa[2*m][3]);
      unsigned int p1a = pk2bf(xa[2*m+1][0], xa[2*m+1][1]);
      unsigned int p1b = pk2bf(xa[2*m+1][2], xa[2*m+1][3]);
      uint2 s0; s0.x = p0a; s0.y = p0b;
      uint2 s1; s1.x = p1a; s1.y = p1b;
      *reinterpret_cast<uint2*>(&Xs[nb + half][4 * l31])     = s0;
      *reinterpret_cast<uint2*>(&Xs[nb + 2 + half][4 * l31]) = s1;
      unsigned int q0a = (unsigned int)__shfl_xor((int)p0a, 32);
      unsigned int q0b = (unsigned int)__shfl_xor((int)p0b, 32);
      unsigned int q1a = (unsigned int)__shfl_xor((int)p1a, 32);
      unsigned int q1b = (unsigned int)__shfl_xor((int)p1b, 32);
      unsigned int A = half ? q0b : p0a;   // local row 4m+0
      unsigned int B = half ? p0b : q0a;   // local row 4m+1
      unsigned int C = half ? q1b : p1a;   // local row 4m+2
      unsigned int D = half ? p1b : q1a;   // local row 4m+3
      const int d0 = 4 * l31 + 2 * half;
      unsigned int wlo0 = __builtin_amdgcn_perm(B, A, 0x05040100u); // n=4m,4m+1 @ d0
      unsigned int wlo1 = __builtin_amdgcn_perm(D, C, 0x05040100u); // n=4m+2,4m+3 @ d0
      unsigned int whi0 = __builtin_amdgcn_perm(B, A, 0x07060302u); // @ d0+1
      unsigned int whi1 = __builtin_amdgcn_perm(D, C, 0x07060302u);
      uint2 wv0; wv0.x = wlo0; wv0.y = wlo1;
      uint2 wv1; wv1.x = whi0; wv1.y = whi1;
      *reinterpret_cast<uint2*>(&xtw[d0][4 * m])     = wv0;
      *reinterpret_cast<uint2*>(&xtw[d0 + 1][4 * m]) = wv1;
    }

    // ---- prefetch next tile ----
    if(tt + 1 < TPB){
      const float* xp = xw + (size_t)(tt + 1) * 64 * DDIM;
      #pragma unroll
      for(int c = 0; c < 8; ++c)
        xa[c] = *reinterpret_cast<const f32x4*>(xp + c * 256);
    }

    // ---- phase A: M = X @ qk^T (A from own Xs strip, B from qs; intra-wave) ----
    f32x4 macc[4];
    #pragma unroll
    for(int i = 0; i < 4; ++i) macc[i] = {0.f,0.f,0.f,0.f};
    __builtin_amdgcn_s_setprio(1);
    #pragma unroll
    for(int step = 0; step < 4; ++step){
      short8 a = *reinterpret_cast<const short8*>(&Xs[wr0 + l15][step * 32 + g * 8]);
      #pragma unroll
      for(int st = 0; st < 4; ++st){
        short8 bq = *reinterpret_cast<const short8*>(&qs[st * 16 + l15][step * 32 + g * 8]);
        macc[st] = __builtin_amdgcn_mfma_f32_16x16x32_bf16(a, bq, macc[st], 0, 0, 0);
      }
    }
    __builtin_amdgcn_s_setprio(0);

    // ---- sigmoid + eps, normalize over 64 slots; W stays in registers ----
    float att[4][4];
    float rinv[4];
    #pragma unroll
    for(int st = 0; st < 4; ++st){
      #pragma unroll
      for(int r = 0; r < 4; ++r)
        att[st][r] = __builtin_amdgcn_rcpf(1.f + __expf(-macc[st][r])) + 1e-8f;
    }
    #pragma unroll
    for(int r = 0; r < 4; ++r){
      float s = att[0][r] + att[1][r] + att[2][r] + att[3][r];
      s += __shfl_xor(s, 1); s += __shfl_xor(s, 2);
      s += __shfl_xor(s, 4); s += __shfl_xor(s, 8);
      rinv[r] = __builtin_amdgcn_rcpf(s);
    }
    // lane (l15,g) holds W[n=g*4+r][slot=st*16+l15] == A-frag (row=slot, k=n) for K=16
    short4v wfrag[4];
    #pragma unroll
    for(int st = 0; st < 4; ++st){
      unsigned int u0 = pk2bf(att[st][0] * rinv[0], att[st][1] * rinv[1]);
      unsigned int u1 = pk2bf(att[st][2] * rinv[2], att[st][3] * rinv[3]);
      short4v wf;
      __builtin_memcpy(&wf, &u0, 4);
      __builtin_memcpy(reinterpret_cast<char*>(&wf) + 4, &u1, 4);
      wfrag[st] = wf;
    }

    // ---- T-phase: T += W_w^T @ X_w, K=16, per-wave, zero barriers ----
    __builtin_amdgcn_s_setprio(1);
    #pragma unroll
    for(int et = 0; et < 8; ++et){
      short4v xt = *reinterpret_cast<const short4v*>(&xtw[et * 16 + l15][4 * g]);
#if __has_builtin(__builtin_amdgcn_mfma_f32_16x16x16bf16_1k)
      #pragma unroll
      for(int sta = 0; sta < 4; ++sta)
        sacc[sta][et] = __builtin_amdgcn_mfma_f32_16x16x16bf16_1k(
            wfrag[sta], xt, sacc[sta][et], 0, 0, 0);
#else
      // fallback: zero-padded K=32 (real n at k=g*8+j, j=0..3; zeros elsewhere)
      short8 b8 = {xt[0], xt[1], xt[2], xt[3], 0, 0, 0, 0};
      #pragma unroll
      for(int sta = 0; sta < 4; ++sta){
        short8 a8 = {wfrag[sta][0], wfrag[sta][1], wfrag[sta][2], wfrag[sta][3], 0, 0, 0, 0};
        sacc[sta][et] = __builtin_amdgcn_mfma_f32_16x16x32_bf16(a8, b8, sacc[sta][et], 0, 0, 0);
      }
#endif
    }
    __builtin_amdgcn_s_setprio(0);
  }

  // ---- epilogue: sum the 4 waves' T via LDS, write bf16 partial (coalesced) ----
  lds_barrier();                       // all tile work done; smem reusable
  float* stg = (float*)smem;           // 4 waves x 2048 f32 = 32 KB
  unsigned short* po = partials + (size_t)blockIdx.x * (KSLOT * EH);
  #pragma unroll
  for(int sta = 0; sta < 4; ++sta){
    #pragma unroll
    for(int et = 0; et < 8; ++et)
      #pragma unroll
      for(int r = 0; r < 4; ++r)
        stg[wave * 2048 + (g * 4 + r) * 128 + et * 16 + l15] = sacc[sta][et][r];
    lds_barrier();
    {
      int i8 = tid * 8;                // 0..2047, 8 consecutive elems per thread
      float v[8];
      #pragma unroll
      for(int j = 0; j < 8; ++j)
        v[j] = stg[i8 + j] + stg[2048 + i8 + j] + stg[4096 + i8 + j] + stg[6144 + i8 + j];
      union { short8 s; unsigned int u[4]; } pk;
      pk.u[0] = pk2bf(v[0], v[1]);
      pk.u[1] = pk2bf(v[2], v[3]);
      pk.u[2] = pk2bf(v[4], v[5]);
      pk.u[3] = pk2bf(v[6], v[7]);
      *reinterpret_cast<short8*>(po + sta * 2048 + i8) = pk.s;
    }
    lds_barrier();
  }
}

// ---- reduce: T[b][s][:] = sum over 64 bf16 block-partials, then out = T @ Wv ----
__global__ void reduce_kernel(const unsigned short* __restrict__ partials,
                              const float* __restrict__ Wv, float* __restrict__ out){
  int bs = blockIdx.x;             // 0..511 = b*64 + slot
  int b  = bs >> 6;
  int s  = bs & 63;
  __shared__ float Tl[128];
  int t = threadIdx.x;             // 128 threads = d, then e
  const unsigned short* pb = partials + (size_t)b * BLK_PER_B * (KSLOT * EH) + s * EH + t;
  float acc = 0.f;
  #pragma unroll 8
  for(int i = 0; i < BLK_PER_B; ++i)
    acc += bf2f(pb[(size_t)i * (KSLOT * EH)]);
  Tl[t] = acc;
  __syncthreads();
  float o = 0.f;
  #pragma unroll 8
  for(int d = 0; d < 128; ++d) o += Tl[d] * Wv[d * 128 + t];
  out[bs * 128 + t] = o;
}

extern "C" void kernel_launch(void* const* d_in, const int* in_sizes, int n_in,
                              void* d_out, int out_size, void* d_ws, size_t ws_size,
                              hipStream_t stream){
  const float* X  = (const float*)d_in[0];
  const float* S  = (const float*)d_in[1];
  const float* Wk = (const float*)d_in[2];
  const float* Wq = (const float*)d_in[3];
  const float* Wv = (const float*)d_in[4];
  float* out = (float*)d_out;

  char* ws = (char*)d_ws;
  unsigned short* qk       = (unsigned short*)(ws);           // 128 KB
  unsigned short* partials = (unsigned short*)(ws + 131072);  // 512 * 16 KB = 8.4 MB

  hipLaunchKernelGGL(prep_qk_kernel, dim3(512), dim3(128), 0, stream, S, Wq, Wk, qk);
  hipLaunchKernelGGL(sse_main_kernel, dim3(N_BATCH * BLK_PER_B), dim3(256), 0, stream,
                     X, qk, partials);
  hipLaunchKernelGGL(reduce_kernel, dim3(512), dim3(128), 0, stream, partials, Wv, out);
}

// Round 22
// 45.873 us; speedup vs baseline: 1.3535x; 1.1137x over previous
//
#include <hip/hip_runtime.h>
#include <hip/hip_bf16.h>

typedef __attribute__((ext_vector_type(8))) short short8;
typedef __attribute__((ext_vector_type(4))) short short4v;
typedef __attribute__((ext_vector_type(4))) float f32x4;

#define N_BATCH 8
#define N_ROWS 32768
#define DDIM 128
#define KSLOT 64
#define EH 128
#define TPB 8                  // tiles per block
#define BLK_PER_B 64           // 512 tiles / TPB
#define SCALE 0.08838834764831845f

__device__ inline unsigned short f2bf(float f){
  unsigned int u = __builtin_bit_cast(unsigned int, f);
  u = (u + 0x7FFFu + ((u >> 16) & 1u)) >> 16;
  return (unsigned short)u;
}
__device__ inline float bf2f(unsigned short h){
  unsigned int u = ((unsigned int)h) << 16;
  return __builtin_bit_cast(float, u);
}

__device__ inline unsigned int pk2bf(float lo, float hi){
  __hip_bfloat162 h = __float22bfloat162_rn(float2{lo, hi});
  unsigned int u;
  __builtin_memcpy(&u, &h, 4);
  return u;
}

__device__ inline void lds_barrier(){
  asm volatile("s_waitcnt lgkmcnt(0)" ::: "memory");
  __builtin_amdgcn_s_barrier();
}

// ---- prep: qk[b][s][d] = scale*(S@Wq)@Wk^T, bf16; 256 thr, split-h chains ----
__global__ void prep_qk_kernel(const float* __restrict__ S, const float* __restrict__ Wq,
                               const float* __restrict__ Wk, unsigned short* __restrict__ qk){
  int bs = blockIdx.x;             // 0..511 = b*64 + slot
  __shared__ float srow[128];
  __shared__ float part[2][128];
  __shared__ float qrow[128];
  int t  = threadIdx.x;            // 256 threads
  int th = t & 127;
  int hh = t >> 7;                 // 0 or 1
  if(t < 128) srow[t] = S[bs * 128 + t];
  __syncthreads();
  {
    float acc = 0.f;
    const float* wq = Wq + (hh * 64) * 128 + th;
    #pragma unroll 8
    for(int h = 0; h < 64; ++h) acc += srow[hh * 64 + h] * wq[h * 128];
    part[hh][th] = acc;
  }
  __syncthreads();
  if(t < 128) qrow[t] = part[0][t] + part[1][t];
  __syncthreads();
  {
    float acc = 0.f;
    const float* wk = Wk + th * 128 + hh * 64;
    #pragma unroll 8
    for(int e = 0; e < 64; ++e) acc += qrow[hh * 64 + e] * wk[e];
    part[hh][th] = acc;
  }
  __syncthreads();
  if(t < 128)
    qk[bs * 128 + t] = f2bf((part[0][t] + part[1][t]) * SCALE);
}

// ---- main fused kernel: zero barriers in the tile loop; waves independent ----
__global__ __launch_bounds__(256, 1) void sse_main_kernel(
    const float* __restrict__ X, const unsigned short* __restrict__ qkg,
    unsigned short* __restrict__ partials)
{
  // manual carve of shared memory so the epilogue can reuse it
  __shared__ char smem[55296];     // qs 17408 | Xs 17408 | Xtw 20480
  unsigned short (*qs)[136]  = (unsigned short(*)[136])(smem);
  unsigned short (*Xs)[136]  = (unsigned short(*)[136])(smem + 17408);
  unsigned short (*Xtw)[20]  = (unsigned short(*)[20]) (smem + 34816); // [4*128][20]

  const int tid  = threadIdx.x;
  const int wave = tid >> 6;
  const int lane = tid & 63;
  const int l15  = lane & 15;
  const int g    = lane >> 4;
  const int l31  = lane & 31;
  const int half = lane >> 5;

  const int b  = blockIdx.x / BLK_PER_B;
  const int tb = blockIdx.x % BLK_PER_B;

  const float* Xb = X + (size_t)b * N_ROWS * DDIM;
  const unsigned short* qkb = qkg + b * KSLOT * EH;

  // ---- stage qk (16 KB) coalesced ----
  #pragma unroll
  for(int i = 0; i < 4; ++i){
    int o = (i * 256 + tid) * 8;
    *reinterpret_cast<short8*>(&qs[o >> 7][o & 127]) =
        *reinterpret_cast<const short8*>(qkb + o);
  }

  f32x4 sacc[4][8];   // T[slot=sta*16+g*4+r][d=et*16+l15], per-wave full T
  #pragma unroll
  for(int i = 0; i < 4; ++i)
    #pragma unroll
    for(int j = 0; j < 8; ++j) sacc[i][j] = {0.f, 0.f, 0.f, 0.f};

  const float* xw = Xb + (size_t)(tb * TPB * 64 + wave * 16) * DDIM + lane * 4;

  f32x4 xa[8];
  #pragma unroll
  for(int c = 0; c < 8; ++c)
    xa[c] = *reinterpret_cast<const f32x4*>(xw + c * 256);

  lds_barrier();    // qs visible; the ONLY barrier before the epilogue

  const int wr0 = wave * 16;
  unsigned short (*xtw)[20] = &Xtw[wave * 128];   // this wave's [128][20] scratch

  #pragma unroll
  for(int tt = 0; tt < TPB; ++tt){

    // ---- pack xa -> Xs (row-major) + xtw (transposed) via reg-exchange ----
    #pragma unroll
    for(int m = 0; m < 4; ++m){
      const int nb = wr0 + 4 * m;
      unsigned int p0a = pk2bf(xa[2*m][0],   xa[2*m][1]);
      unsigned int p0b = pk2bf(xa[2*m][2],   xa[2*m][3]);
      unsigned int p1a = pk2bf(xa[2*m+1][0], xa[2*m+1][1]);
      unsigned int p1b = pk2bf(xa[2*m+1][2], xa[2*m+1][3]);
      uint2 s0; s0.x = p0a; s0.y = p0b;
      uint2 s1; s1.x = p1a; s1.y = p1b;
      *reinterpret_cast<uint2*>(&Xs[nb + half][4 * l31])     = s0;
      *reinterpret_cast<uint2*>(&Xs[nb + 2 + half][4 * l31]) = s1;
      unsigned int q0a = (unsigned int)__shfl_xor((int)p0a, 32);
      unsigned int q0b = (unsigned int)__shfl_xor((int)p0b, 32);
      unsigned int q1a = (unsigned int)__shfl_xor((int)p1a, 32);
      unsigned int q1b = (unsigned int)__shfl_xor((int)p1b, 32);
      unsigned int A = half ? q0b : p0a;   // local row 4m+0
      unsigned int B = half ? p0b : q0a;   // local row 4m+1
      unsigned int C = half ? q1b : p1a;   // local row 4m+2
      unsigned int D = half ? p1b : q1a;   // local row 4m+3
      const int d0 = 4 * l31 + 2 * half;
      unsigned int wlo0 = __builtin_amdgcn_perm(B, A, 0x05040100u); // n=4m,4m+1 @ d0
      unsigned int wlo1 = __builtin_amdgcn_perm(D, C, 0x05040100u); // n=4m+2,4m+3 @ d0
      unsigned int whi0 = __builtin_amdgcn_perm(B, A, 0x07060302u); // @ d0+1
      unsigned int whi1 = __builtin_amdgcn_perm(D, C, 0x07060302u);
      uint2 wv0; wv0.x = wlo0; wv0.y = wlo1;
      uint2 wv1; wv1.x = whi0; wv1.y = whi1;
      *reinterpret_cast<uint2*>(&xtw[d0][4 * m])     = wv0;
      *reinterpret_cast<uint2*>(&xtw[d0 + 1][4 * m]) = wv1;
    }

    // ---- prefetch next tile ----
    if(tt + 1 < TPB){
      const float* xp = xw + (size_t)(tt + 1) * 64 * DDIM;
      #pragma unroll
      for(int c = 0; c < 8; ++c)
        xa[c] = *reinterpret_cast<const f32x4*>(xp + c * 256);
    }

    // ---- phase A: M = X @ qk^T (A from own Xs strip, B from qs; intra-wave) ----
    f32x4 macc[4];
    #pragma unroll
    for(int i = 0; i < 4; ++i) macc[i] = {0.f,0.f,0.f,0.f};
    __builtin_amdgcn_s_setprio(1);
    #pragma unroll
    for(int step = 0; step < 4; ++step){
      short8 a = *reinterpret_cast<const short8*>(&Xs[wr0 + l15][step * 32 + g * 8]);
      #pragma unroll
      for(int st = 0; st < 4; ++st){
        short8 bq = *reinterpret_cast<const short8*>(&qs[st * 16 + l15][step * 32 + g * 8]);
        macc[st] = __builtin_amdgcn_mfma_f32_16x16x32_bf16(a, bq, macc[st], 0, 0, 0);
      }
    }
    __builtin_amdgcn_s_setprio(0);

    // ---- sigmoid + eps, normalize over 64 slots; W stays in registers ----
    float att[4][4];
    float rinv[4];
    #pragma unroll
    for(int st = 0; st < 4; ++st){
      #pragma unroll
      for(int r = 0; r < 4; ++r)
        att[st][r] = __builtin_amdgcn_rcpf(1.f + __expf(-macc[st][r])) + 1e-8f;
    }
    #pragma unroll
    for(int r = 0; r < 4; ++r){
      float s = att[0][r] + att[1][r] + att[2][r] + att[3][r];
      s += __shfl_xor(s, 1); s += __shfl_xor(s, 2);
      s += __shfl_xor(s, 4); s += __shfl_xor(s, 8);
      rinv[r] = __builtin_amdgcn_rcpf(s);
    }
    // lane (l15,g) holds W[n=g*4+r][slot=st*16+l15] == A-frag (row=slot, k=n) for K=16
    short4v wfrag[4];
    #pragma unroll
    for(int st = 0; st < 4; ++st){
      unsigned int u0 = pk2bf(att[st][0] * rinv[0], att[st][1] * rinv[1]);
      unsigned int u1 = pk2bf(att[st][2] * rinv[2], att[st][3] * rinv[3]);
      short4v wf;
      __builtin_memcpy(&wf, &u0, 4);
      __builtin_memcpy(reinterpret_cast<char*>(&wf) + 4, &u1, 4);
      wfrag[st] = wf;
    }

    // ---- T-phase: T += W_w^T @ X_w, K=16, per-wave, zero barriers ----
    __builtin_amdgcn_s_setprio(1);
    #pragma unroll
    for(int et = 0; et < 8; ++et){
      short4v xt = *reinterpret_cast<const short4v*>(&xtw[et * 16 + l15][4 * g]);
#if __has_builtin(__builtin_amdgcn_mfma_f32_16x16x16bf16_1k)
      #pragma unroll
      for(int sta = 0; sta < 4; ++sta)
        sacc[sta][et] = __builtin_amdgcn_mfma_f32_16x16x16bf16_1k(
            wfrag[sta], xt, sacc[sta][et], 0, 0, 0);
#else
      // fallback: zero-padded K=32 (real n at k=g*8+j, j=0..3; zeros elsewhere)
      short8 b8 = {xt[0], xt[1], xt[2], xt[3], 0, 0, 0, 0};
      #pragma unroll
      for(int sta = 0; sta < 4; ++sta){
        short8 a8 = {wfrag[sta][0], wfrag[sta][1], wfrag[sta][2], wfrag[sta][3], 0, 0, 0, 0};
        sacc[sta][et] = __builtin_amdgcn_mfma_f32_16x16x32_bf16(a8, b8, sacc[sta][et], 0, 0, 0);
      }
#endif
    }
    __builtin_amdgcn_s_setprio(0);
  }

  // ---- epilogue: sum the 4 waves' T via LDS, write bf16 partial (coalesced) ----
  lds_barrier();                       // all tile work done; smem reusable
  float* stg = (float*)smem;           // 4 waves x 2048 f32 = 32 KB
  unsigned short* po = partials + (size_t)blockIdx.x * (KSLOT * EH);
  #pragma unroll
  for(int sta = 0; sta < 4; ++sta){
    #pragma unroll
    for(int et = 0; et < 8; ++et)
      #pragma unroll
      for(int r = 0; r < 4; ++r)
        stg[wave * 2048 + (g * 4 + r) * 128 + et * 16 + l15] = sacc[sta][et][r];
    lds_barrier();
    {
      int i8 = tid * 8;                // 0..2047, 8 consecutive elems per thread
      float v[8];
      #pragma unroll
      for(int j = 0; j < 8; ++j)
        v[j] = stg[i8 + j] + stg[2048 + i8 + j] + stg[4096 + i8 + j] + stg[6144 + i8 + j];
      union { short8 s; unsigned int u[4]; } pk;
      pk.u[0] = pk2bf(v[0], v[1]);
      pk.u[1] = pk2bf(v[2], v[3]);
      pk.u[2] = pk2bf(v[4], v[5]);
      pk.u[3] = pk2bf(v[6], v[7]);
      *reinterpret_cast<short8*>(po + sta * 2048 + i8) = pk.s;
    }
    lds_barrier();
  }
}

// ---- reduce: 256 thr; i-range and Wv-dot each split over 2 halves ----
__global__ void reduce_kernel(const unsigned short* __restrict__ partials,
                              const float* __restrict__ Wv, float* __restrict__ out){
  int bs = blockIdx.x;             // 0..511 = b*64 + slot
  int b  = bs >> 6;
  int s  = bs & 63;
  __shared__ float part[2][128];
  __shared__ float Tl[128];
  int t  = threadIdx.x;            // 256 threads
  int th = t & 127;                // d index
  int ih = t >> 7;                 // 0 or 1
  {
    const unsigned short* pb = partials +
        (size_t)(b * BLK_PER_B + ih * 32) * (KSLOT * EH) + s * EH + th;
    float acc = 0.f;
    #pragma unroll 8
    for(int i = 0; i < 32; ++i)
      acc += bf2f(pb[(size_t)i * (KSLOT * EH)]);
    part[ih][th] = acc;
  }
  __syncthreads();
  if(t < 128) Tl[t] = part[0][t] + part[1][t];
  __syncthreads();
  {
    float o = 0.f;
    const float* wv = Wv + (ih * 64) * 128 + th;
    #pragma unroll 8
    for(int d = 0; d < 64; ++d) o += Tl[ih * 64 + d] * wv[d * 128];
    part[ih][th] = o;
  }
  __syncthreads();
  if(t < 128)
    out[bs * 128 + t] = part[0][t] + part[1][t];
}

extern "C" void kernel_launch(void* const* d_in, const int* in_sizes, int n_in,
                              void* d_out, int out_size, void* d_ws, size_t ws_size,
                              hipStream_t stream){
  const float* X  = (const float*)d_in[0];
  const float* S  = (const float*)d_in[1];
  const float* Wk = (const float*)d_in[2];
  const float* Wq = (const float*)d_in[3];
  const float* Wv = (const float*)d_in[4];
  float* out = (float*)d_out;

  char* ws = (char*)d_ws;
  unsigned short* qk       = (unsigned short*)(ws);           // 128 KB
  unsigned short* partials = (unsigned short*)(ws + 131072);  // 512 * 16 KB = 8.4 MB

  hipLaunchKernelGGL(prep_qk_kernel, dim3(512), dim3(256), 0, stream, S, Wq, Wk, qk);
  hipLaunchKernelGGL(sse_main_kernel, dim3(N_BATCH * BLK_PER_B), dim3(256), 0, stream,
                     X, qk, partials);
  hipLaunchKernelGGL(reduce_kernel, dim3(512), dim3(256), 0, stream, partials, Wv, out);
}